// Round 1
// baseline (223.027 us; speedup 1.0000x reference)
//
#include <hip/hip_runtime.h>
#include <hip/hip_fp16.h>
#include <stdint.h>

typedef float floatx4 __attribute__((ext_vector_type(4)));
typedef short short8 __attribute__((ext_vector_type(8)));

constexpr int I_SZ = 256, O_SZ = 256, NCOL = 512, B_SZ = 4096;
constexpr int KSTEPS = 264;           // 256 RBF steps + 8 silu steps
constexpr float GSTEP = 4.0f / 7.0f;  // linspace(-2,2,8) step
constexpr float NLOG2E = -1.44269504088896f;

// pack two fp32 -> two bf16 (truncate) in one v_perm_b32
__device__ __forceinline__ uint32_t pk_bf16(float lo, float hi) {
  return __builtin_amdgcn_perm(__float_as_uint(hi), __float_as_uint(lo), 0x07060302u);
}
__device__ __forceinline__ short rne_bf16(float f) {
  uint32_t u = __float_as_uint(f);
  return (short)((u + 0x7FFFu + ((u >> 16) & 1u)) >> 16);
}

__device__ __forceinline__ void gload_lds16(const void* g, void* l) {
  __builtin_amdgcn_global_load_lds((const __attribute__((address_space(1))) void*)g,
                                   (__attribute__((address_space(3))) void*)l,
                                   16, 0, 0);
}

__device__ __forceinline__ float silu_f(float a) {
  return a * __builtin_amdgcn_rcpf(1.f + __builtin_amdgcn_exp2f(a * NLOG2E));
}

// ---------------- weight packing: Wpack[kb][n][gp][e] bf16, gp = g ^ (n&7); 8 elems/thread ----------------
__global__ void pack_weights(const float* __restrict__ rw, const float* __restrict__ cw,
                             const float* __restrict__ swre, const float* __restrict__ swim,
                             short* __restrict__ wpack) {
  int idx = blockIdx.x * 256 + threadIdx.x;   // enumerates (kb, n, gp): 264*512*8
  int kb = idx >> 12;
  int rem = idx & 4095;
  int n = rem >> 3, gp = rem & 7;
  int g = gp ^ (n & 7);
  int o = n >> 1, c = n & 1;
  float w[8];
  if (kb < 256) {
    const float* W = (c ? cw : rw) + (((size_t)kb * O_SZ + o) << 6) + (g << 3);
    float4 a = *(const float4*)W;
    float4 b = *(const float4*)(W + 4);
    w[0] = a.x; w[1] = a.y; w[2] = a.z; w[3] = a.w;
    w[4] = b.x; w[5] = b.y; w[6] = b.z; w[7] = b.w;
  } else {
    int kp0 = ((kb - 256) << 6) + (g << 3);
    #pragma unroll
    for (int e = 0; e < 8; ++e) {
      int kp = kp0 + e, i = kp >> 1, ci = kp & 1;
      float a = swre[i * O_SZ + o], b = swim[i * O_SZ + o];
      w[e] = (c == 0) ? (ci == 0 ? a : -b) : (ci == 0 ? b : a);
    }
  }
  uint32_t h[8];
  #pragma unroll
  for (int e = 0; e < 8; ++e) h[e] = (uint32_t)(uint16_t)rne_bf16(w[e]);
  uint4 val = make_uint4(h[0] | (h[1] << 16), h[2] | (h[3] << 16),
                         h[4] | (h[5] << 16), h[6] | (h[7] << 16));
  *(uint4*)(wpack + (size_t)idx * 8) = val;
}

// ---------------- x transpose: xT[c][i][b] fp16 from x[b][i] fp32 ----------------
__global__ void transpose_x(const float* __restrict__ xre, const float* __restrict__ xim,
                            __half* __restrict__ xT) {
  __shared__ float tile[64][65];
  int bt = blockIdx.x & 63;           // b-tile (4096/64)
  int it = (blockIdx.x >> 6) & 3;     // i-tile (256/64)
  int c  = blockIdx.x >> 8;           // plane
  const float* src = (c ? xim : xre);
  int b0 = bt << 6, i0 = it << 6;
  int t = threadIdx.x;
  int il = t & 63, bh = t >> 6;       // load: consecutive t -> consecutive i (coalesced)
  #pragma unroll
  for (int k = 0; k < 16; ++k) {
    int bl = bh + (k << 2);
    tile[bl][il] = src[(size_t)(b0 + bl) * I_SZ + i0 + il];
  }
  __syncthreads();
  int bl2 = t & 63, ih = t >> 6;      // store: consecutive t -> consecutive b (coalesced)
  __half* dst = xT + ((size_t)c * I_SZ + i0) * B_SZ + b0;
  #pragma unroll
  for (int k = 0; k < 16; ++k) {
    int il2 = ih + (k << 2);
    dst[(size_t)il2 * B_SZ + bl2] = __float2half(tile[bl2][il2]);
  }
}

// ---------------- bias column sums ----------------
__global__ void bias_sums(const float* __restrict__ bre, const float* __restrict__ bim,
                          float* __restrict__ bsum) {
  int n = blockIdx.x, o = n >> 1, l = threadIdx.x;
  const float* src = ((n & 1) ? bim : bre) + o;
  float s = 0.f;
  #pragma unroll
  for (int a = 0; a < 4; ++a) s += src[(size_t)(a * 64 + l) * O_SZ];
  #pragma unroll
  for (int off = 32; off; off >>= 1) s += __shfl_down(s, off, 64);
  if (l == 0) bsum[n] = s;
}

// ---------------- main fused GEMM ----------------
// block: 128 rows x 256 cols, 8 waves (2x4 of 64x64), split-K = 4 chunks of (64 RBF + 2 silu) steps.
// LDS: B triple-buffered (prefetch depth 2, counted vmcnt(4) never drains the in-flight stage),
//      A double-buffered (built by VALU one step ahead, overlapped with MFMA).
__global__ __launch_bounds__(512, 2) void cvkan_gemm(
    const float* __restrict__ xre, const float* __restrict__ xim,
    const __half* __restrict__ xT,
    const short* __restrict__ wpack, const float* __restrict__ bsum,
    float* __restrict__ out) {
  __shared__ __align__(16) short As[2 * 128 * 64];   // [buf][row][gp][e], gp = g ^ (row&7)
  __shared__ __align__(16) short Bs[3 * 256 * 64];   // [buf][col][gp][e], gp = g ^ (col&7)

  const int tid = threadIdx.x;
  const int bid = blockIdx.x;
  const int kch = bid & 3;              // K-chunk; with nt below, each XCD sees one ~2MB wpack slice
  const int mn = bid >> 2;
  const int mt = mn >> 1, nt = mn & 1;
  const int b0 = mt * 128, n0 = nt * 256;
  const int l = tid & 63, w = tid >> 6;
  const int wr = w >> 2, wc = w & 3;    // 2x4 wave grid, each wave 64x64
  const int lm = l & 15, q = l >> 4;
  const int r = tid >> 2, p = tid & 3;  // A-build: row r (0..127), u-pair p

  const __half* xTre = xT;
  const __half* xTim = xT + (size_t)I_SZ * B_SZ;

  short* ac = As;       short* an  = As + 8192;
  short* bc = Bs;       short* bn1 = Bs + 16384;   short* bn2 = Bs + 32768;

  floatx4 acc[4][4] = {};

  // step index: j<64 -> RBF step kch*64+j ; j in {64,65} -> silu step 256 + kch*2 + (j-64)
  auto sidx = [&](int j) { return j < 64 ? kch * 64 + j : 256 + kch * 2 + (j - 64); };

  // stage one 32KB B tile (256 cols x 64 k, bf16): 4 x (512 threads x 16B) contiguous
  auto stage_B = [&](short* bdst, int s) {
    const short* src = wpack + (((size_t)s * NCOL + n0) << 6) + (tid << 3);
    short* ldst = bdst + (w << 9);   // wave-uniform base; HW adds lane*16B
    gload_lds16(src,         ldst);
    gload_lds16(src +  4096, ldst +  4096);
    gload_lds16(src +  8192, ldst +  8192);
    gload_lds16(src + 12288, ldst + 12288);
  };

  // build one 16KB A tile: 512 threads, each = 1 row x 2 u-groups (10 exp2)
  auto build_A = [&](short* adst, int s) {
    if (s < 256) {
      float xr = __half2float(xTre[(size_t)s * B_SZ + b0 + r]);
      float xi = __half2float(xTim[(size_t)s * B_SZ + b0 + r]);
      float eiv[8];
      #pragma unroll
      for (int v = 0; v < 8; ++v) {
        float d = xi - (-2.0f + v * GSTEP);
        eiv[v] = __builtin_amdgcn_exp2f(d * d * NLOG2E);
      }
      #pragma unroll
      for (int uu = 0; uu < 2; ++uu) {
        int u = p * 2 + uu;
        float d = xr - (-2.0f + u * GSTEP);
        float er = __builtin_amdgcn_exp2f(d * d * NLOG2E);
        uint4 val = make_uint4(pk_bf16(er * eiv[0], er * eiv[1]),
                               pk_bf16(er * eiv[2], er * eiv[3]),
                               pk_bf16(er * eiv[4], er * eiv[5]),
                               pk_bf16(er * eiv[6], er * eiv[7]));
        *(uint4*)(adst + (r << 6) + ((u ^ (r & 7)) << 3)) = val;
      }
    } else {
      int sl = s - 256;                // silu step: A[b, 2i+c] = silu(x_c[b,i])
      #pragma unroll
      for (int gg = 0; gg < 2; ++gg) {
        int g = p * 2 + gg;
        const float* pr = xre + (size_t)(b0 + r) * I_SZ + (sl << 5) + (g << 2);
        const float* pi = xim + (size_t)(b0 + r) * I_SZ + (sl << 5) + (g << 2);
        uint4 val = make_uint4(pk_bf16(silu_f(pr[0]), silu_f(pi[0])),
                               pk_bf16(silu_f(pr[1]), silu_f(pi[1])),
                               pk_bf16(silu_f(pr[2]), silu_f(pi[2])),
                               pk_bf16(silu_f(pr[3]), silu_f(pi[3])));
        *(uint4*)(adst + (r << 6) + ((g ^ (r & 7)) << 3)) = val;
      }
    }
  };

  // prologue: stage steps 0,1; build A for step 0. vmcnt(4): step-0 loads landed, step-1 in flight.
  stage_B(bc, sidx(0));
  stage_B(bn1, sidx(1));
  build_A(ac, sidx(0));
  asm volatile("s_waitcnt vmcnt(4) lgkmcnt(0)" ::: "memory");
  __builtin_amdgcn_s_barrier();

  for (int j = 0; j < 66; ++j) {
    if (j < 64) stage_B(bn2, sidx(j + 2));   // prefetch depth 2 (HBM/L2 latency spans a full step)
    if (j < 65) build_A(an, sidx(j + 1));    // VALU build overlaps this step's MFMA

    // --- B fragments from current buffer: n = lm, k = q*8+j (and +32) ---
    short8 bf[4][2];
    #pragma unroll
    for (int nn = 0; nn < 4; ++nn) {
      int col = wc * 64 + nn * 16 + lm;
      const short* bp = bc + (col << 6);
      bf[nn][0] = *(const short8*)(bp + ((q       ^ (col & 7)) << 3));
      bf[nn][1] = *(const short8*)(bp + (((q + 4) ^ (col & 7)) << 3));
    }
    __builtin_amdgcn_s_setprio(1);
    #pragma unroll
    for (int mm = 0; mm < 4; ++mm) {
      int row = wr * 64 + mm * 16 + lm;
      const short* ap = ac + (row << 6);
      short8 a0 = *(const short8*)(ap + ((q       ^ (row & 7)) << 3));
      short8 a1 = *(const short8*)(ap + (((q + 4) ^ (row & 7)) << 3));
      #pragma unroll
      for (int nn = 0; nn < 4; ++nn) {
        acc[mm][nn] = __builtin_amdgcn_mfma_f32_16x16x32_bf16(a0, bf[nn][0], acc[mm][nn], 0, 0, 0);
        acc[mm][nn] = __builtin_amdgcn_mfma_f32_16x16x32_bf16(a1, bf[nn][1], acc[mm][nn], 0, 0, 0);
      }
    }
    __builtin_amdgcn_s_setprio(0);

    if (j < 65) {
      // counted drain: keep this step's 4 prefetch loads in flight across the barrier (T4);
      // lgkmcnt(0) publishes the A-build ds_writes before any wave crosses.
      if (j < 64) asm volatile("s_waitcnt vmcnt(4) lgkmcnt(0)" ::: "memory");
      else        asm volatile("s_waitcnt vmcnt(0) lgkmcnt(0)" ::: "memory");
      __builtin_amdgcn_s_barrier();
    }
    short* t = bc; bc = bn1; bn1 = bn2; bn2 = t;   // rotate B triple-buffer
    t = ac; ac = an; an = t;                       // swap A double-buffer
  }

  // --- epilogue: C/D layout col=lane&15, row=q*4+reg; bias added by chunk-3 only ---
  #pragma unroll
  for (int nn = 0; nn < 4; ++nn) {
    int col = n0 + wc * 64 + nn * 16 + lm;
    float bv = (kch == 3) ? bsum[col] : 0.0f;
    #pragma unroll
    for (int mm = 0; mm < 4; ++mm) {
      int row0 = b0 + wr * 64 + mm * 16 + (q << 2);
      #pragma unroll
      for (int r2 = 0; r2 < 4; ++r2)
        atomicAdd(out + (size_t)(row0 + r2) * NCOL + col, acc[mm][nn][r2] + bv);
    }
  }
}

extern "C" void kernel_launch(void* const* d_in, const int* in_sizes, int n_in,
                              void* d_out, int out_size, void* d_ws, size_t ws_size,
                              hipStream_t stream) {
  const float* xre  = (const float*)d_in[0];
  const float* xim  = (const float*)d_in[1];
  const float* rw   = (const float*)d_in[2];
  const float* cw   = (const float*)d_in[3];
  const float* swre = (const float*)d_in[4];
  const float* swim = (const float*)d_in[5];
  const float* bre  = (const float*)d_in[6];
  const float* bim  = (const float*)d_in[7];
  float* out = (float*)d_out;

  size_t wpack_bytes = (size_t)KSTEPS * NCOL * 64 * 2;   // 16.5 MiB
  short* wpack = (short*)d_ws;
  float* bsum  = (float*)((char*)d_ws + wpack_bytes);
  __half* xT   = (__half*)((char*)d_ws + wpack_bytes + 2048);  // 2 planes * 256*4096 fp16 = 4 MiB

  hipMemsetAsync(d_out, 0, (size_t)B_SZ * NCOL * sizeof(float), stream);
  pack_weights<<<(KSTEPS * NCOL * 8) / 256, 256, 0, stream>>>(rw, cw, swre, swim, wpack);
  transpose_x<<<512, 256, 0, stream>>>(xre, xim, xT);
  bias_sums<<<NCOL, 64, 0, stream>>>(bre, bim, bsum);
  cvkan_gemm<<<256, 512, 0, stream>>>(xre, xim, xT, wpack, bsum, out);
}